// Round 2
// baseline (123.576 us; speedup 1.0000x reference)
//
#include <hip/hip_runtime.h>
#include <math.h>
#include <stdint.h>

#define N 4096
#define Dm 1024
#define BK 64
#define NT (Dm / BK)   // 16 K-tiles
#define NCB (N / 64)   // 64 column-partials per row
#define NPART 512      // combine blocks -> scalar partials

typedef __attribute__((ext_vector_type(8))) short bf16x8;
typedef __attribute__((ext_vector_type(4))) float f32x4;

typedef const void __attribute__((address_space(1)))* gas_t;
typedef void __attribute__((address_space(3)))* las_t;

static __device__ __forceinline__ void gload_lds16(const void* g, void* l) {
    // async global->LDS, 16B per lane; LDS dest is wave-uniform base + lane*16
    __builtin_amdgcn_global_load_lds((gas_t)g, (las_t)l, 16, 0, 0);
}

static __device__ __forceinline__ unsigned short f2bf(float f) {
    unsigned int u = __float_as_uint(f);
    unsigned int r = (u + 0x7fff + ((u >> 16) & 1)) >> 16;  // RNE
    return (unsigned short)r;
}

// Kernel 1: convert A,P -> bf16 + per-row diag dot + L2 partial. One wave per row.
__global__ __launch_bounds__(256) void prep_kernel(const float* __restrict__ A,
                                                   const float* __restrict__ P,
                                                   unsigned short* __restrict__ Abf,
                                                   unsigned short* __restrict__ Pbf,
                                                   float* __restrict__ D,
                                                   float* __restrict__ rowl2) {
    int t = threadIdx.x;
    int lane = t & 63;
    int row = blockIdx.x * 4 + (t >> 6);
    const float4* a4 = (const float4*)(A + (size_t)row * Dm);
    const float4* p4 = (const float4*)(P + (size_t)row * Dm);
    ushort4* ao = (ushort4*)(Abf + (size_t)row * Dm);
    ushort4* po = (ushort4*)(Pbf + (size_t)row * Dm);
    float dot = 0.0f, l2 = 0.0f;
#pragma unroll
    for (int c = 0; c < 4; ++c) {
        int idx = c * 64 + lane;              // coalesced within the wave
        float4 a = a4[idx], p = p4[idx];
        ushort4 ab, pb;
        ab.x = f2bf(a.x); ab.y = f2bf(a.y); ab.z = f2bf(a.z); ab.w = f2bf(a.w);
        pb.x = f2bf(p.x); pb.y = f2bf(p.y); pb.z = f2bf(p.z); pb.w = f2bf(p.w);
        ao[idx] = ab; po[idx] = pb;
        dot += a.x * p.x + a.y * p.y + a.z * p.z + a.w * p.w;
        l2  += a.x * a.x + a.y * a.y + a.z * a.z + a.w * a.w
             + p.x * p.x + p.y * p.y + p.z * p.z + p.w * p.w;
    }
#pragma unroll
    for (int off = 32; off; off >>= 1) {
        dot += __shfl_xor(dot, off, 64);
        l2  += __shfl_xor(l2,  off, 64);
    }
    if (lane == 0) {
        D[row]     = dot;
        rowl2[row] = l2;
    }
}

// ---------------------------------------------------------------------------
// Kernel 2: 256x256 tile, 8 waves, 4-phase/K-tile schedule with counted vmcnt
// (T3+T4), conflict-free XOR-chunk LDS (T2-equiv), setprio around MFMA (T5).
//
// Pipeline invariants (hand-verified inventory, per-thread vmem instrs):
//   prologue: stage T0.A(4) T0.B(4) T1.A(4) T1.B(4); vmcnt(8) -> T0 resident.
//   group t: ph0 stages T(t+1).A (4) into As[(t+1)&1] (idle buffer);
//            ph1/ph2 stage T(t+2).B halves (2+2) into Bs[t&1].B, whose data
//            was fully consumed at ph0 (B-frags live in registers);
//            group-end s_waitcnt vmcnt(4) -> queue was [T(t+1).B x4,
//            T(t+1).A x4, T(t+2).B x4]; completes oldest 8 -> T(t+1) fully
//            resident, only the two newest B-halves in flight.
//            t==NT-2: vmcnt(0).  t==NT-1: no stages, no waits.
//   Every LDS overwrite is issue-ordered after the s_barrier that follows the
//   lgkmcnt(0)+MFMA consuming that region (cross-wave safe) -> no WAR race.
//   All in-loop conditionals are block-uniform -> no barrier divergence.
// ---------------------------------------------------------------------------
#define STAGE_TILE(gp, lp, kt) do {                                            \
        gload_lds16((gp) + (kt),                    (lp)         + tid * 8);   \
        gload_lds16((gp) + (kt) +  64 * (size_t)Dm, (lp) + 4096  + tid * 8);   \
        gload_lds16((gp) + (kt) + 128 * (size_t)Dm, (lp) + 8192  + tid * 8);   \
        gload_lds16((gp) + (kt) + 192 * (size_t)Dm, (lp) + 12288 + tid * 8);   \
    } while (0)

#define STAGE_B_HALF(lpB, kt, h) do {                                          \
        gload_lds16(gB + (kt) + ((h) ? 128 * (size_t)Dm : (size_t)0),          \
                    (lpB) + (h) * 8192 + tid * 8);                             \
        gload_lds16(gB + (kt) + ((h) ? 192 * (size_t)Dm : 64 * (size_t)Dm),    \
                    (lpB) + (h) * 8192 + 4096 + tid * 8);                      \
    } while (0)

#define DO_MFMA(I, AK0, AK1)                                                   \
    _Pragma("unroll")                                                          \
    for (int j = 0; j < 4; ++j)                                                \
        acc[I][j] = __builtin_amdgcn_mfma_f32_16x16x32_bf16(AK0, bfrag[j][0], acc[I][j], 0, 0, 0); \
    _Pragma("unroll")                                                          \
    for (int j = 0; j < 4; ++j)                                                \
        acc[I][j] = __builtin_amdgcn_mfma_f32_16x16x32_bf16(AK1, bfrag[j][1], acc[I][j], 0, 0, 0);

#define PHASE_BODY(P, STAGE_STMT, TAIL)                                        \
    {                                                                          \
        bf16x8 a0k0 = *(const bf16x8*)(aT + (2*(P))     * 16 * BK + aoff0);    \
        bf16x8 a0k1 = *(const bf16x8*)(aT + (2*(P))     * 16 * BK + aoff1);    \
        bf16x8 a1k0 = *(const bf16x8*)(aT + (2*(P) + 1) * 16 * BK + aoff0);    \
        bf16x8 a1k1 = *(const bf16x8*)(aT + (2*(P) + 1) * 16 * BK + aoff1);    \
        STAGE_STMT;                                                            \
        __builtin_amdgcn_s_barrier();                                          \
        asm volatile("s_waitcnt lgkmcnt(0)" ::: "memory");                     \
        __builtin_amdgcn_sched_barrier(0);                                     \
        __builtin_amdgcn_s_setprio(1);                                         \
        DO_MFMA(2*(P),     a0k0, a0k1)                                         \
        DO_MFMA(2*(P) + 1, a1k0, a1k1)                                         \
        __builtin_amdgcn_s_setprio(0);                                         \
        TAIL;                                                                  \
    }

__global__ __launch_bounds__(512, 2) void npair_mfma(const unsigned short* __restrict__ Abf,
                                                     const unsigned short* __restrict__ Pbf,
                                                     const float* __restrict__ D,
                                                     float* __restrict__ Mpart,
                                                     float* __restrict__ Spart) {
    __shared__ unsigned short As[2][256 * BK];   // 64 KB (double-buffered A tile)
    __shared__ unsigned short Bs[2][256 * BK];   // 64 KB — total 128 KB, 1 block/CU

    int tid = threadIdx.x;
    int lane = tid & 63;
    int wid = tid >> 6;
    int wr = wid >> 2, wc = wid & 3;             // 2x4 waves, each owns 128x64 output

    // XCD-aware bijective swizzle: 256 blocks -> 8 XCDs x 32 blocks; each XCD
    // gets a compact 4x8 patch of the 16x16 tile grid (A/B panel L2 locality).
    int bid = blockIdx.y * gridDim.x + blockIdx.x;
    int xcd = bid & 7, lid = bid >> 3;           // lid in [0,32)
    int by = (xcd >> 1) * 4 + (lid >> 3);        // [0,16)
    int bx = (xcd & 1) * 8 + (lid & 7);          // [0,16)
    int row0 = by * 256, col0 = bx * 256;

    // Staging: slot L = row*8 + c holds global k-chunk (c ^ (row&7)); swizzle in
    // the GLOBAL address, LDS dest lane-linear (global_load_lds requirement).
    int srow = tid >> 3;                          // 0..63 (row within 64-row band)
    int kcol = (tid & 7) ^ (srow & 7);            // same for all 4 bands (64 % 8 == 0)
    const unsigned short* gA = Abf + (size_t)(row0 + srow) * Dm + (kcol << 3);
    const unsigned short* gB = Pbf + (size_t)(col0 + srow) * Dm + (kcol << 3);

    // Prologue: fully stage tiles 0 and 1 (16 vmem instrs), wait oldest 8 (=T0).
    STAGE_TILE(gA, &As[0][0], 0);
    STAGE_TILE(gB, &Bs[0][0], 0);
    STAGE_TILE(gA, &As[1][0], BK);
    STAGE_TILE(gB, &Bs[1][0], BK);
    asm volatile("s_waitcnt vmcnt(8)" ::: "memory");
    __builtin_amdgcn_s_barrier();

    // Fragment-read addressing: frag-row & 7 == lane & 7 (16 | row offsets),
    // so the XOR folds into a per-thread-constant chunk offset.
    int l15 = lane & 15;
    int aoff0 = (((lane >> 4)    ) ^ (lane & 7)) << 3;   // ks=0 chunk (shorts)
    int aoff1 = (((lane >> 4) + 4) ^ (lane & 7)) << 3;   // ks=1 chunk
    const unsigned short* aBase = &As[0][0] + (wr * 128 + l15) * BK;
    const unsigned short* bBase = &Bs[0][0] + (wc * 64  + l15) * BK;

    f32x4 acc[8][4] = {};
    bf16x8 bfrag[4][2];

#pragma unroll 2
    for (int t = 0; t < NT; ++t) {
        const unsigned short* aT = aBase + (t & 1) * (256 * BK);
        const unsigned short* bT = bBase + (t & 1) * (256 * BK);
        unsigned short* stA = &As[(t + 1) & 1][0];
        unsigned short* stB = &Bs[t & 1][0];

        // ph0: all B-frags -> registers (B region of this buffer dead after this
        // phase) + A rows 0,1; stage next A tile into the idle buffer.
#pragma unroll
        for (int j = 0; j < 4; ++j) {
            bfrag[j][0] = *(const bf16x8*)(bT + j * 16 * BK + aoff0);
            bfrag[j][1] = *(const bf16x8*)(bT + j * 16 * BK + aoff1);
        }
        PHASE_BODY(0,
            { if (t >= 1 && t + 1 < NT) STAGE_TILE(gA, stA, (t + 1) * BK); },
            __builtin_amdgcn_s_barrier())
        // ph1/ph2: A rows 2..5; stage T(t+2).B halves into the (dead) B region.
        PHASE_BODY(1,
            { if (t + 2 < NT) STAGE_B_HALF(stB, (t + 2) * BK, 0); },
            __builtin_amdgcn_s_barrier())
        PHASE_BODY(2,
            { if (t + 2 < NT) STAGE_B_HALF(stB, (t + 2) * BK, 1); },
            __builtin_amdgcn_s_barrier())
        // ph3: A rows 6,7; group-end counted wait (never 0 until the tail).
        PHASE_BODY(3,
            { },
            {
                if (t < NT - 2)       { asm volatile("s_waitcnt vmcnt(4)" ::: "memory"); }
                else if (t == NT - 2) { asm volatile("s_waitcnt vmcnt(0)" ::: "memory"); }
                if (t < NT - 1) __builtin_amdgcn_s_barrier();
            })
    }

    // Fence: keep the epilogue's D loads / Mpart stores OUT of the counted
    // vmcnt region above (they are loop-invariant loads the MIR scheduler
    // could otherwise hoist past the inline-asm waits -> inventory corruption).
    __builtin_amdgcn_sched_barrier(0);

    // Epilogue. C/D layout: col = lane&15, row = (lane>>4)*4 + reg  [m89/m91].
    // D read straight from global (4096 floats, L2-resident after prep).
    int cb = bx * 4 + wc;                        // column-partial slot, NCB=64
#pragma unroll
    for (int i = 0; i < 8; ++i) {
        int rloc = wr * 128 + i * 16 + ((lane >> 4) << 2);
#pragma unroll
        for (int e = 0; e < 4; ++e) {
            int gr = row0 + rloc + e;
            float Dv = D[gr];
            float xs[4];
            float m = -INFINITY;
#pragma unroll
            for (int j = 0; j < 4; ++j) {
                int gc = col0 + wc * 64 + j * 16 + (lane & 15);
                float x = acc[i][j][e] - Dv;
                if (gr == gc) x = -INFINITY;      // mask diagonal
                xs[j] = x;
                m = fmaxf(m, x);
            }
#pragma unroll
            for (int off = 8; off; off >>= 1) m = fmaxf(m, __shfl_xor(m, off, 64));
            float s = 0.0f;
#pragma unroll
            for (int j = 0; j < 4; ++j) s += __expf(xs[j] - m);   // exp(-inf)=0 on diag
#pragma unroll
            for (int off = 8; off; off >>= 1) s += __shfl_xor(s, off, 64);
            if ((lane & 15) == 0) {
                Mpart[(size_t)gr * NCB + cb] = m;
                Spart[(size_t)gr * NCB + cb] = s;
            }
        }
    }
}

// Kernel 3: per-row logsumexp combine; each block (8 rows) emits ONE partial pair.
__global__ __launch_bounds__(256) void combine_rows(const float* __restrict__ Mpart,
                                                    const float* __restrict__ Spart,
                                                    const float* __restrict__ rowl2,
                                                    float* __restrict__ partL,
                                                    float* __restrict__ partR) {
    int t = threadIdx.x;
    int lane = t & 63;
    int w = t >> 6;
    __shared__ float ls[8];
#pragma unroll
    for (int r = 0; r < 2; ++r) {
        int row = blockIdx.x * 8 + w * 2 + r;
        float mp = Mpart[(size_t)row * NCB + lane];
        float sp = Spart[(size_t)row * NCB + lane];
        float m = mp;
#pragma unroll
        for (int off = 32; off; off >>= 1) m = fmaxf(m, __shfl_xor(m, off, 64));
        float s = sp * __expf(mp - m);
#pragma unroll
        for (int off = 32; off; off >>= 1) s += __shfl_xor(s, off, 64);
        if (lane == 0) ls[w * 2 + r] = m + logf(__expf(-m) + s);  // log1p(sum exp), safe
    }
    __syncthreads();
    if (t == 0) {
        int r8 = blockIdx.x * 8;
        float L = 0.0f, R = 0.0f;
#pragma unroll
        for (int r = 0; r < 8; ++r) { L += ls[r]; R += rowl2[r8 + r]; }
        partL[blockIdx.x] = L;
        partR[blockIdx.x] = R;
    }
}

// Kernel 4: final scalar from 512 partial pairs.
__global__ __launch_bounds__(256) void final_reduce(const float* __restrict__ partL,
                                                    const float* __restrict__ partR,
                                                    float* __restrict__ out) {
    int t = threadIdx.x;
    float accL = partL[t] + partL[t + 256];
    float acc2 = partR[t] + partR[t + 256];
#pragma unroll
    for (int off = 32; off; off >>= 1) {
        accL += __shfl_xor(accL, off, 64);
        acc2 += __shfl_xor(acc2, off, 64);
    }
    __shared__ float sa[4], sb[4];
    int wave = t >> 6;
    if ((t & 63) == 0) { sa[wave] = accL; sb[wave] = acc2; }
    __syncthreads();
    if (t == 0) {
        float L  = sa[0] + sa[1] + sa[2] + sa[3];
        float l2 = sb[0] + sb[1] + sb[2] + sb[3];
        out[0] = L / (float)N + 0.02f * (l2 / (float)N);
    }
}

extern "C" void kernel_launch(void* const* d_in, const int* in_sizes, int n_in,
                              void* d_out, int out_size, void* d_ws, size_t ws_size,
                              hipStream_t stream) {
    const float* A = (const float*)d_in[0];
    const float* P = (const float*)d_in[1];
    float* out = (float*)d_out;

    unsigned short* Abf = (unsigned short*)d_ws;            // N*Dm bf16 = 8 MiB
    unsigned short* Pbf = Abf + (size_t)N * Dm;             // 8 MiB
    float* D     = (float*)(Pbf + (size_t)N * Dm);          // N
    float* rowl2 = D + N;                                   // N
    float* partL = rowl2 + N;                               // NPART
    float* partR = partL + NPART;                           // NPART
    float* Mpart = partR + NPART;                           // N*NCB = 1 MiB
    float* Spart = Mpart + (size_t)N * NCB;                 // 1 MiB

    prep_kernel<<<N / 4, 256, 0, stream>>>(A, P, Abf, Pbf, D, rowl2);
    dim3 grid(16, 16);                                      // 256 blocks = 1/CU
    npair_mfma<<<grid, 512, 0, stream>>>(Abf, Pbf, D, Mpart, Spart);
    combine_rows<<<N / 8, 256, 0, stream>>>(Mpart, Spart, rowl2, partL, partR);
    final_reduce<<<1, 256, 0, stream>>>(partL, partR, out);
}

// Round 3
// 122.271 us; speedup vs baseline: 1.0107x; 1.0107x over previous
//
#include <hip/hip_runtime.h>
#include <math.h>
#include <stdint.h>

#define N 4096
#define Dm 1024
#define BK 64
#define NT (Dm / BK)   // 16 K-tiles
#define NCB (N / 64)   // 64 column-partials per row
#define NPART 512      // combine blocks -> scalar partials

typedef __attribute__((ext_vector_type(8))) short bf16x8;
typedef __attribute__((ext_vector_type(4))) float f32x4;

typedef const void __attribute__((address_space(1)))* gas_t;
typedef void __attribute__((address_space(3)))* las_t;

static __device__ __forceinline__ void gload_lds16(const void* g, void* l) {
    // async global->LDS, 16B per lane; LDS dest is wave-uniform base + lane*16
    __builtin_amdgcn_global_load_lds((gas_t)g, (las_t)l, 16, 0, 0);
}

static __device__ __forceinline__ unsigned short f2bf(float f) {
    unsigned int u = __float_as_uint(f);
    unsigned int r = (u + 0x7fff + ((u >> 16) & 1)) >> 16;  // RNE
    return (unsigned short)r;
}

// Kernel 1: convert A,P -> bf16 + per-row diag dot + L2 partial. One wave per row.
__global__ __launch_bounds__(256) void prep_kernel(const float* __restrict__ A,
                                                   const float* __restrict__ P,
                                                   unsigned short* __restrict__ Abf,
                                                   unsigned short* __restrict__ Pbf,
                                                   float* __restrict__ D,
                                                   float* __restrict__ rowl2) {
    int t = threadIdx.x;
    int lane = t & 63;
    int row = blockIdx.x * 4 + (t >> 6);
    const float4* a4 = (const float4*)(A + (size_t)row * Dm);
    const float4* p4 = (const float4*)(P + (size_t)row * Dm);
    ushort4* ao = (ushort4*)(Abf + (size_t)row * Dm);
    ushort4* po = (ushort4*)(Pbf + (size_t)row * Dm);
    float dot = 0.0f, l2 = 0.0f;
#pragma unroll
    for (int c = 0; c < 4; ++c) {
        int idx = c * 64 + lane;              // coalesced within the wave
        float4 a = a4[idx], p = p4[idx];
        ushort4 ab, pb;
        ab.x = f2bf(a.x); ab.y = f2bf(a.y); ab.z = f2bf(a.z); ab.w = f2bf(a.w);
        pb.x = f2bf(p.x); pb.y = f2bf(p.y); pb.z = f2bf(p.z); pb.w = f2bf(p.w);
        ao[idx] = ab; po[idx] = pb;
        dot += a.x * p.x + a.y * p.y + a.z * p.z + a.w * p.w;
        l2  += a.x * a.x + a.y * a.y + a.z * a.z + a.w * a.w
             + p.x * p.x + p.y * p.y + p.z * p.z + p.w * p.w;
    }
#pragma unroll
    for (int off = 32; off; off >>= 1) {
        dot += __shfl_xor(dot, off, 64);
        l2  += __shfl_xor(l2,  off, 64);
    }
    if (lane == 0) {
        D[row]     = dot;
        rowl2[row] = l2;
    }
}

// ---------------------------------------------------------------------------
// Kernel 2: 256x256 tile, 8 waves, 4-phase/K-tile with ONE-PHASE-AHEAD frag
// pipelining (R2 fix: ds_read issue overlaps prior phase's MFMA; compiler
// emits the counted lgkmcnt), single counted vmcnt(4) per tile at ph3 (never
// 0 until t=14), XOR-chunk conflict-free LDS, setprio around MFMA clusters.
//
// Residency/WAR invariants (hand-verified):
//   vmem queue entering tile t: [B(t+1) x4]. ph0 +A(t+1), ph1/2 +B(t+2).
//   ph3 vmcnt(4): completes B(t+1)+A(t+1) -> barrier -> prefetch t+1 frags.
//   t=14: vmcnt(0); t=15: no stages/waits.
//   WAR (stage vs prior readers): every frag read is consumed by an MFMA
//   whose compiler-lgkmcnt precedes (sched_barrier-pinned) the phase-end
//   s_barrier; all stage issues are on the far side of that barrier.
// ---------------------------------------------------------------------------
#define STAGE_TILE(gp, lp, kt) do {                                            \
        gload_lds16((gp) + (kt),                    (lp)         + tid * 8);   \
        gload_lds16((gp) + (kt) +  64 * (size_t)Dm, (lp) + 4096  + tid * 8);   \
        gload_lds16((gp) + (kt) + 128 * (size_t)Dm, (lp) + 8192  + tid * 8);   \
        gload_lds16((gp) + (kt) + 192 * (size_t)Dm, (lp) + 12288 + tid * 8);   \
    } while (0)

#define STAGE_B_HALF(lpB, kt, h) do {                                          \
        gload_lds16(gB + (kt) + ((h) ? 128 * (size_t)Dm : (size_t)0),          \
                    (lpB) + (h) * 8192 + tid * 8);                             \
        gload_lds16(gB + (kt) + ((h) ? 192 * (size_t)Dm : 64 * (size_t)Dm),    \
                    (lpB) + (h) * 8192 + 4096 + tid * 8);                      \
    } while (0)

// read rows rg0*16+l15 and (rg0+1)*16+l15, both ks-chunks, into dst[0..3]
#define READ_A4(dst, buf, rg0) do {                                            \
        dst[0] = *(const bf16x8*)((buf) + ((rg0)     * 16) * BK + aoff0);      \
        dst[1] = *(const bf16x8*)((buf) + ((rg0)     * 16) * BK + aoff1);      \
        dst[2] = *(const bf16x8*)((buf) + ((rg0) + 1) * 16 * BK + aoff0);      \
        dst[3] = *(const bf16x8*)((buf) + ((rg0) + 1) * 16 * BK + aoff1);      \
    } while (0)

#define READ_B8(PAR, buf) do {                                                 \
        _Pragma("unroll")                                                      \
        for (int j = 0; j < 4; ++j) {                                          \
            bfr[PAR][j][0] = *(const bf16x8*)((buf) + j * 16 * BK + aoff0);    \
            bfr[PAR][j][1] = *(const bf16x8*)((buf) + j * 16 * BK + aoff1);    \
        }                                                                      \
    } while (0)

// phase p MFMA cluster: output rows I=2p,2p+1; A pair-array ap, B parity BP
#define MFMA_PH(P, ap, BP)                                                     \
    _Pragma("unroll")                                                          \
    for (int j = 0; j < 4; ++j)                                                \
        acc[2*(P)][j]   = __builtin_amdgcn_mfma_f32_16x16x32_bf16(ap[0], bfr[BP][j][0], acc[2*(P)][j],   0, 0, 0); \
    _Pragma("unroll")                                                          \
    for (int j = 0; j < 4; ++j)                                                \
        acc[2*(P)][j]   = __builtin_amdgcn_mfma_f32_16x16x32_bf16(ap[1], bfr[BP][j][1], acc[2*(P)][j],   0, 0, 0); \
    _Pragma("unroll")                                                          \
    for (int j = 0; j < 4; ++j)                                                \
        acc[2*(P)+1][j] = __builtin_amdgcn_mfma_f32_16x16x32_bf16(ap[2], bfr[BP][j][0], acc[2*(P)+1][j], 0, 0, 0); \
    _Pragma("unroll")                                                          \
    for (int j = 0; j < 4; ++j)                                                \
        acc[2*(P)+1][j] = __builtin_amdgcn_mfma_f32_16x16x32_bf16(ap[3], bfr[BP][j][1], acc[2*(P)+1][j], 0, 0, 0);

// One K-tile, CUR/NXT as literals (rule #20: all reg-array indices static).
#define TILE_BODY(CUR, NXT) do {                                               \
        const unsigned short* aT  = aBase + (CUR) * 16384;                     \
        const unsigned short* aTn = aBase + (NXT) * 16384;                     \
        const unsigned short* bTn = bBase + (NXT) * 16384;                     \
        unsigned short* stA = &As[NXT][0];                                     \
        unsigned short* stB = &Bs[CUR][0];                                     \
        /* ph0: consume aF[0]+bfr[CUR]; prefetch aF[1]<-rows 2,3; stage A(t+1) */ \
        READ_A4(aF[1], aT, 2);                                                 \
        if (t >= 1 && t <= 14) STAGE_TILE(gA, stA, (t + 1) * BK);              \
        __builtin_amdgcn_sched_barrier(0);                                     \
        __builtin_amdgcn_s_setprio(1);                                         \
        MFMA_PH(0, aF[0], CUR)                                                 \
        __builtin_amdgcn_s_setprio(0);                                         \
        __builtin_amdgcn_sched_barrier(0);                                     \
        __builtin_amdgcn_s_barrier();                                          \
        /* ph1: consume aF[1]; prefetch aF[0]<-rows 4,5; stage B(t+2) half0 */ \
        READ_A4(aF[0], aT, 4);                                                 \
        if (t <= 13) STAGE_B_HALF(stB, (t + 2) * BK, 0);                       \
        __builtin_amdgcn_sched_barrier(0);                                     \
        __builtin_amdgcn_s_setprio(1);                                         \
        MFMA_PH(1, aF[1], CUR)                                                 \
        __builtin_amdgcn_s_setprio(0);                                         \
        __builtin_amdgcn_sched_barrier(0);                                     \
        __builtin_amdgcn_s_barrier();                                          \
        /* ph2: consume aF[0]; prefetch aF[1]<-rows 6,7; stage B(t+2) half1 */ \
        READ_A4(aF[1], aT, 6);                                                 \
        if (t <= 13) STAGE_B_HALF(stB, (t + 2) * BK, 1);                       \
        __builtin_amdgcn_sched_barrier(0);                                     \
        __builtin_amdgcn_s_setprio(1);                                         \
        MFMA_PH(2, aF[0], CUR)                                                 \
        __builtin_amdgcn_s_setprio(0);                                         \
        __builtin_amdgcn_sched_barrier(0);                                     \
        __builtin_amdgcn_s_barrier();                                          \
        /* ph3: residency wait + next-tile frag prefetch, then MFMA aF[1] */   \
        if (t <= 13)      { asm volatile("s_waitcnt vmcnt(4)" ::: "memory"); } \
        else if (t == 14) { asm volatile("s_waitcnt vmcnt(0)" ::: "memory"); } \
        if (t <= 14) {                                                         \
            __builtin_amdgcn_s_barrier();                                      \
            __builtin_amdgcn_sched_barrier(0);                                 \
            READ_B8(NXT, bTn);                                                 \
            READ_A4(aF[0], aTn, 0);                                            \
        }                                                                      \
        __builtin_amdgcn_sched_barrier(0);                                     \
        __builtin_amdgcn_s_setprio(1);                                         \
        MFMA_PH(3, aF[1], CUR)                                                 \
        __builtin_amdgcn_s_setprio(0);                                         \
        __builtin_amdgcn_sched_barrier(0);                                     \
        if (t <= 13) __builtin_amdgcn_s_barrier();                             \
    } while (0)

__global__ __launch_bounds__(512, 2) void npair_mfma(const unsigned short* __restrict__ Abf,
                                                     const unsigned short* __restrict__ Pbf,
                                                     const float* __restrict__ D,
                                                     float* __restrict__ Mpart,
                                                     float* __restrict__ Spart) {
    __shared__ unsigned short As[2][256 * BK];   // 64 KB (double-buffered A tile)
    __shared__ unsigned short Bs[2][256 * BK];   // 64 KB — total 128 KB, 1 block/CU

    int tid = threadIdx.x;
    int lane = tid & 63;
    int wid = tid >> 6;
    int wr = wid >> 2, wc = wid & 3;             // 2x4 waves, each owns 128x64 output

    // XCD-aware bijective swizzle: 256 blocks -> 8 XCDs x 32 blocks; each XCD
    // gets a compact 4x8 patch of the 16x16 tile grid (A/B panel L2 locality).
    int bid = blockIdx.y * gridDim.x + blockIdx.x;
    int xcd = bid & 7, lid = bid >> 3;           // lid in [0,32)
    int by = (xcd >> 1) * 4 + (lid >> 3);        // [0,16)
    int bx = (xcd & 1) * 8 + (lid & 7);          // [0,16)
    int row0 = by * 256, col0 = bx * 256;

    // Staging: slot L = row*8 + c holds global k-chunk (c ^ (row&7)); swizzle in
    // the GLOBAL address, LDS dest lane-linear (global_load_lds requirement).
    int srow = tid >> 3;                          // 0..63 (row within 64-row band)
    int kcol = (tid & 7) ^ (srow & 7);            // same for all 4 bands (64 % 8 == 0)
    const unsigned short* gA = Abf + (size_t)(row0 + srow) * Dm + (kcol << 3);
    const unsigned short* gB = Pbf + (size_t)(col0 + srow) * Dm + (kcol << 3);

    // Prologue: fully stage tiles 0 and 1 (16 vmem instrs), wait oldest 8 (=T0).
    STAGE_TILE(gA, &As[0][0], 0);
    STAGE_TILE(gB, &Bs[0][0], 0);
    STAGE_TILE(gA, &As[1][0], BK);
    STAGE_TILE(gB, &Bs[1][0], BK);
    asm volatile("s_waitcnt vmcnt(8)" ::: "memory");
    __builtin_amdgcn_s_barrier();
    __builtin_amdgcn_sched_barrier(0);

    // Fragment-read addressing: frag-row & 7 == lane & 7 (16 | row offsets),
    // so the XOR folds into a per-thread-constant chunk offset.
    int l15 = lane & 15;
    int aoff0 = (((lane >> 4)    ) ^ (lane & 7)) << 3;   // ks=0 chunk (shorts)
    int aoff1 = (((lane >> 4) + 4) ^ (lane & 7)) << 3;   // ks=1 chunk
    const unsigned short* aBase = &As[0][0] + (wr * 128 + l15) * BK;
    const unsigned short* bBase = &Bs[0][0] + (wc * 64  + l15) * BK;

    f32x4 acc[8][4] = {};
    bf16x8 bfr[2][4][2];   // B frags, tile-parity double-buffered
    bf16x8 aF[2][4];       // A rowgroup pair, phase-parity double-buffered

    // Pre-loop frag reads for tile 0 (consumed at t=0 ph0).
    READ_B8(0, bBase);
    READ_A4(aF[0], aBase, 0);

    for (int tt = 0; tt < NT / 2; ++tt) {
        int t = 2 * tt;
        TILE_BODY(0, 1);
        t = 2 * tt + 1;
        TILE_BODY(1, 0);
    }

    // Fence: keep epilogue memory ops out of the counted region above.
    __builtin_amdgcn_sched_barrier(0);

    // Epilogue. C/D layout: col = lane&15, row = (lane>>4)*4 + reg  [m89/m91].
    // D read straight from global (4096 floats, L2-resident after prep).
    int cb = bx * 4 + wc;                        // column-partial slot, NCB=64
#pragma unroll
    for (int i = 0; i < 8; ++i) {
        int rloc = wr * 128 + i * 16 + ((lane >> 4) << 2);
#pragma unroll
        for (int e = 0; e < 4; ++e) {
            int gr = row0 + rloc + e;
            float Dv = D[gr];
            float xs[4];
            float m = -INFINITY;
#pragma unroll
            for (int j = 0; j < 4; ++j) {
                int gc = col0 + wc * 64 + j * 16 + (lane & 15);
                float x = acc[i][j][e] - Dv;
                if (gr == gc) x = -INFINITY;      // mask diagonal
                xs[j] = x;
                m = fmaxf(m, x);
            }
#pragma unroll
            for (int off = 8; off; off >>= 1) m = fmaxf(m, __shfl_xor(m, off, 64));
            float s = 0.0f;
#pragma unroll
            for (int j = 0; j < 4; ++j) s += __expf(xs[j] - m);   // exp(-inf)=0 on diag
#pragma unroll
            for (int off = 8; off; off >>= 1) s += __shfl_xor(s, off, 64);
            if ((lane & 15) == 0) {
                Mpart[(size_t)gr * NCB + cb] = m;
                Spart[(size_t)gr * NCB + cb] = s;
            }
        }
    }
}

// Kernel 3: per-row logsumexp combine; each block (8 rows) emits ONE partial pair.
__global__ __launch_bounds__(256) void combine_rows(const float* __restrict__ Mpart,
                                                    const float* __restrict__ Spart,
                                                    const float* __restrict__ rowl2,
                                                    float* __restrict__ partL,
                                                    float* __restrict__ partR) {
    int t = threadIdx.x;
    int lane = t & 63;
    int w = t >> 6;
    __shared__ float ls[8];
#pragma unroll
    for (int r = 0; r < 2; ++r) {
        int row = blockIdx.x * 8 + w * 2 + r;
        float mp = Mpart[(size_t)row * NCB + lane];
        float sp = Spart[(size_t)row * NCB + lane];
        float m = mp;
#pragma unroll
        for (int off = 32; off; off >>= 1) m = fmaxf(m, __shfl_xor(m, off, 64));
        float s = sp * __expf(mp - m);
#pragma unroll
        for (int off = 32; off; off >>= 1) s += __shfl_xor(s, off, 64);
        if (lane == 0) ls[w * 2 + r] = m + logf(__expf(-m) + s);  // log1p(sum exp), safe
    }
    __syncthreads();
    if (t == 0) {
        int r8 = blockIdx.x * 8;
        float L = 0.0f, R = 0.0f;
#pragma unroll
        for (int r = 0; r < 8; ++r) { L += ls[r]; R += rowl2[r8 + r]; }
        partL[blockIdx.x] = L;
        partR[blockIdx.x] = R;
    }
}

// Kernel 4: final scalar from 512 partial pairs.
__global__ __launch_bounds__(256) void final_reduce(const float* __restrict__ partL,
                                                    const float* __restrict__ partR,
                                                    float* __restrict__ out) {
    int t = threadIdx.x;
    float accL = partL[t] + partL[t + 256];
    float acc2 = partR[t] + partR[t + 256];
#pragma unroll
    for (int off = 32; off; off >>= 1) {
        accL += __shfl_xor(accL, off, 64);
        acc2 += __shfl_xor(acc2, off, 64);
    }
    __shared__ float sa[4], sb[4];
    int wave = t >> 6;
    if ((t & 63) == 0) { sa[wave] = accL; sb[wave] = acc2; }
    __syncthreads();
    if (t == 0) {
        float L  = sa[0] + sa[1] + sa[2] + sa[3];
        float l2 = sb[0] + sb[1] + sb[2] + sb[3];
        out[0] = L / (float)N + 0.02f * (l2 / (float)N);
    }
}

extern "C" void kernel_launch(void* const* d_in, const int* in_sizes, int n_in,
                              void* d_out, int out_size, void* d_ws, size_t ws_size,
                              hipStream_t stream) {
    const float* A = (const float*)d_in[0];
    const float* P = (const float*)d_in[1];
    float* out = (float*)d_out;

    unsigned short* Abf = (unsigned short*)d_ws;            // N*Dm bf16 = 8 MiB
    unsigned short* Pbf = Abf + (size_t)N * Dm;             // 8 MiB
    float* D     = (float*)(Pbf + (size_t)N * Dm);          // N
    float* rowl2 = D + N;                                   // N
    float* partL = rowl2 + N;                               // NPART
    float* partR = partL + NPART;                           // NPART
    float* Mpart = partR + NPART;                           // N*NCB = 1 MiB
    float* Spart = Mpart + (size_t)N * NCB;                 // 1 MiB

    prep_kernel<<<N / 4, 256, 0, stream>>>(A, P, Abf, Pbf, D, rowl2);
    dim3 grid(16, 16);                                      // 256 blocks = 1/CU
    npair_mfma<<<grid, 512, 0, stream>>>(Abf, Pbf, D, Mpart, Spart);
    combine_rows<<<N / 8, 256, 0, stream>>>(Mpart, Spart, rowl2, partL, partR);
    final_reduce<<<1, 256, 0, stream>>>(partL, partR, out);
}